// Round 3
// baseline (367.691 us; speedup 1.0000x reference)
//
#include <hip/hip_runtime.h>
#include <hip/hip_bf16.h>

#define S_DIM 8192
#define B_DIM 32
#define H_DIM 256
#define CH 64                              // number of s-chunks
#define ROWS_PER_CHUNK (S_DIM / CH)        // 128
#define WAVES 4                            // waves per 256-thread block
#define ROWS_PER_WAVE (ROWS_PER_CHUNK / WAVES)  // 32

// Kernel 1: flash-style partial attention over f32 inputs.
// One (chunk, b) per block; one 64-lane wave per row (lane holds 4 h's).
__global__ __launch_bounds__(256, 8) void attn_partial(
    const float* __restrict__ enc, const float* __restrict__ hid,
    float* __restrict__ ws_acc, float* __restrict__ ws_ml)
{
    const int chunk = blockIdx.x;
    const int b     = blockIdx.y;
    const int tid   = threadIdx.x;
    const int w     = tid >> 6;    // wave 0..3
    const int lane  = tid & 63;    // 0..63

    // hid fragment: lane holds h = lane*4 .. lane*4+3
    const float4 hv = *(const float4*)(hid + b * H_DIM + lane * 4);
    const float hf[4] = {hv.x, hv.y, hv.z, hv.w};

    float m = -1e30f, l = 0.f;
    float acc[4] = {0.f, 0.f, 0.f, 0.f};

    const int s0 = chunk * ROWS_PER_CHUNK;
    #pragma unroll 2
    for (int i = 0; i < ROWS_PER_WAVE; i++) {
        const int s = s0 + i * WAVES + w;
        const float4 rv = *(const float4*)(enc + (size_t)s * (B_DIM * H_DIM) + b * H_DIM + lane * 4);
        const float a[4] = {rv.x, rv.y, rv.z, rv.w};

        float d = 0.f;
        #pragma unroll
        for (int j = 0; j < 4; j++) d = fmaf(a[j], hf[j], d);
        // full-wave (64-lane) reduce
        #pragma unroll
        for (int off = 32; off >= 1; off >>= 1)
            d += __shfl_xor(d, off, 64);

        const float mn    = fmaxf(m, d);
        const float alpha = __expf(m - mn);
        const float p     = __expf(d - mn);
        l = l * alpha + p;
        #pragma unroll
        for (int j = 0; j < 4; j++) acc[j] = acc[j] * alpha + p * a[j];
        m = mn;
    }

    // Merge the 4 waves via LDS
    __shared__ float lds_acc[WAVES][H_DIM];  // 4 KB
    __shared__ float lds_ml[WAVES][2];
    #pragma unroll
    for (int j = 0; j < 4; j++) lds_acc[w][lane * 4 + j] = acc[j];
    if (lane == 0) { lds_ml[w][0] = m; lds_ml[w][1] = l; }
    __syncthreads();

    const int h = tid;  // 256 threads == H_DIM
    float mb = -1e30f;
    #pragma unroll
    for (int q = 0; q < WAVES; q++) mb = fmaxf(mb, lds_ml[q][0]);
    float lb = 0.f, cb = 0.f;
    #pragma unroll
    for (int q = 0; q < WAVES; q++) {
        const float cf = __expf(lds_ml[q][0] - mb);
        lb += cf * lds_ml[q][1];
        cb += cf * lds_acc[q][h];
    }
    ws_acc[((size_t)b * CH + chunk) * H_DIM + h] = cb;
    if (tid == 0) {
        ws_ml[(b * CH + chunk) * 2 + 0] = mb;
        ws_ml[(b * CH + chunk) * 2 + 1] = lb;
    }
}

// Kernel 2: combine the CH partials per batch, normalize, write f32.
__global__ __launch_bounds__(256) void attn_final(
    const float* __restrict__ ws_acc, const float* __restrict__ ws_ml,
    float* __restrict__ out)
{
    const int b   = blockIdx.x;
    const int tid = threadIdx.x;
    __shared__ float coef[CH];
    __shared__ float Ls;

    if (tid < CH) {  // exactly wave 0 (CH == 64)
        const float mc = ws_ml[(b * CH + tid) * 2 + 0];
        const float lc = ws_ml[(b * CH + tid) * 2 + 1];
        float M = mc;
        #pragma unroll
        for (int off = 32; off >= 1; off >>= 1)
            M = fmaxf(M, __shfl_xor(M, off, 64));
        const float c = __expf(mc - M);
        float Lp = c * lc;
        #pragma unroll
        for (int off = 32; off >= 1; off >>= 1)
            Lp += __shfl_xor(Lp, off, 64);
        coef[tid] = c;
        if (tid == 0) Ls = Lp;
    }
    __syncthreads();

    float s = 0.f;
    const float* base = ws_acc + (size_t)b * CH * H_DIM + tid;
    #pragma unroll 4
    for (int c2 = 0; c2 < CH; c2++) s += coef[c2] * base[(size_t)c2 * H_DIM];
    out[b * H_DIM + tid] = s / Ls;
}

extern "C" void kernel_launch(void* const* d_in, const int* in_sizes, int n_in,
                              void* d_out, int out_size, void* d_ws, size_t ws_size,
                              hipStream_t stream) {
    const float* enc = (const float*)d_in[0];  // [S, B, H] f32
    const float* hid = (const float*)d_in[1];  // [1, B, H] f32
    float* ws_acc = (float*)d_ws;                          // [B][CH][H] f32, 2 MiB
    float* ws_ml  = ws_acc + (size_t)B_DIM * CH * H_DIM;   // [B][CH][2] f32, 16 KiB
    float* out = (float*)d_out;                            // [B, H] f32

    attn_partial<<<dim3(CH, B_DIM), 256, 0, stream>>>(enc, hid, ws_acc, ws_ml);
    attn_final<<<B_DIM, 256, 0, stream>>>(ws_acc, ws_ml, out);
}